// Round 1
// baseline (779.257 us; speedup 1.0000x reference)
//
#include <hip/hip_runtime.h>

// Problem constants (from reference): N=50000 nodes, D=L=64.
#define N_NODES 50000
#define DIM 64

// ---------------------------------------------------------------------------
// Kernel 1: edge scatter-add.  16 threads per edge, each handling one float4
// chunk of the 64-float source row.  Row loads are coalesced (consecutive
// threads -> consecutive addresses); atomics land on consecutive addresses of
// the destination row.
// ---------------------------------------------------------------------------
__global__ void __launch_bounds__(256) scatter_add_kernel(
        const float* __restrict__ x,
        const int*   __restrict__ edge_src,
        const int*   __restrict__ edge_dst,
        float*       __restrict__ agg,
        int num_edges) {
    int tid = blockIdx.x * 256 + threadIdx.x;
    int e = tid >> 4;              // 16 threads per edge
    if (e >= num_edges) return;
    int c = (tid & 15) << 2;       // float4 chunk offset within the row

    int s = edge_src[e];
    int d = edge_dst[e];

    const float4 v = *reinterpret_cast<const float4*>(x + (size_t)s * DIM + c);
    float* p = agg + (size_t)d * DIM + c;
    atomicAdd(p + 0, v.x);
    atomicAdd(p + 1, v.y);
    atomicAdd(p + 2, v.z);
    atomicAdd(p + 3, v.w);
}

// ---------------------------------------------------------------------------
// Kernel 2: fused residual + dense projection + degree-normalize + ReLU.
// One wave (64 lanes) per node; lane l produces out[n][l].
// W (64x64 fp32 = 16 KB) staged in LDS once per block.  Pooled row staged in
// LDS so the inner loop is a broadcast-read (same addr, conflict-free) times
// a stride-64 column read (2 lanes/bank = free on gfx950, m136).
// Grid is exactly N/4 blocks -> no tail, __syncthreads is safe.
// ---------------------------------------------------------------------------
__global__ void __launch_bounds__(256) project_kernel(
        const float* __restrict__ agg,
        const float* __restrict__ x,
        const float* __restrict__ W,
        const float* __restrict__ bias,
        const float* __restrict__ deg,
        float*       __restrict__ out) {
    __shared__ float Wlds[DIM * DIM];
    __shared__ float sp[4][DIM];

    int t = threadIdx.x;
    // Stage W: 4096 floats / 256 threads = 16 floats each, via float4.
    #pragma unroll
    for (int i = 0; i < 4; ++i) {
        int idx = t * 4 + i * 1024;
        *reinterpret_cast<float4*>(&Wlds[idx]) =
            *reinterpret_cast<const float4*>(&W[idx]);
    }

    int wave = t >> 6;
    int lane = t & 63;
    int node = blockIdx.x * 4 + wave;    // grid = N/4 exactly, no bounds check

    // Pooled row element for this lane (residual self-connection).
    float pv = agg[(size_t)node * DIM + lane] + x[(size_t)node * DIM + lane];
    sp[wave][lane] = pv;
    __syncthreads();   // covers both W staging and sp row staging

    float acc = bias[lane];
    #pragma unroll
    for (int d = 0; d < DIM; ++d) {
        acc = fmaf(sp[wave][d], Wlds[d * DIM + lane], acc);
    }

    float r = acc / deg[node];
    out[(size_t)node * DIM + lane] = fmaxf(r, 0.0f);
}

extern "C" void kernel_launch(void* const* d_in, const int* in_sizes, int n_in,
                              void* d_out, int out_size, void* d_ws, size_t ws_size,
                              hipStream_t stream) {
    const float* x        = (const float*)d_in[0];
    const float* weight   = (const float*)d_in[1];
    const float* bias     = (const float*)d_in[2];
    const float* node_deg = (const float*)d_in[3];
    const int*   edge_src = (const int*)d_in[4];
    const int*   edge_dst = (const int*)d_in[5];
    float* out = (float*)d_out;

    const int E = in_sizes[4];

    float* agg = (float*)d_ws;                       // N*DIM fp32 = 12.8 MB
    const size_t agg_bytes = (size_t)N_NODES * DIM * sizeof(float);

    // d_ws is re-poisoned to 0xAA before every timed call -> zero it here.
    hipMemsetAsync(agg, 0, agg_bytes, stream);

    // Scatter: 16 threads/edge.
    int scatter_threads = E * 16;
    int scatter_blocks = (scatter_threads + 255) / 256;
    scatter_add_kernel<<<scatter_blocks, 256, 0, stream>>>(
        x, edge_src, edge_dst, agg, E);

    // Projection: 1 wave per node, 4 nodes per block. 50000/4 = 12500 exact.
    project_kernel<<<N_NODES / 4, 256, 0, stream>>>(
        agg, x, weight, bias, node_deg, out);
}

// Round 2
// 335.879 us; speedup vs baseline: 2.3201x; 2.3201x over previous
//
#include <hip/hip_runtime.h>

#define N_NODES 50000
#define DIM 64
#define E_EDGES 800000

// ---------------------------------------------------------------------------
// Counting-sort-by-dst pipeline (replaces 51.2M fp32 global atomics, which
// write through the non-coherent per-XCD L2 at 16 B/atomic = 819 MB HBM
// writes, with 1.6M int atomics + pure gather reads).
// ---------------------------------------------------------------------------

// Kernel 1: histogram of edge_dst.
__global__ void __launch_bounds__(256) hist_kernel(
        const int* __restrict__ edge_dst, int* __restrict__ counts, int E) {
    int i = blockIdx.x * 256 + threadIdx.x;
    if (i < E) atomicAdd(&counts[edge_dst[i]], 1);
}

// Kernel 2: exclusive scan over N_NODES bins. Single block, 1024 threads,
// each owning a contiguous chunk; block-level Hillis-Steele over chunk sums.
__global__ void __launch_bounds__(1024) scan_kernel(
        const int* __restrict__ counts,
        int* __restrict__ offsets,
        int* __restrict__ cursor) {
    __shared__ int sums[1024];
    int t = threadIdx.x;
    const int chunk = (N_NODES + 1023) / 1024;   // 49
    int begin = t * chunk;
    int end = begin + chunk; if (end > N_NODES) end = N_NODES;

    int s = 0;
    for (int i = begin; i < end && i < N_NODES; ++i) s += counts[i];
    sums[t] = s;
    __syncthreads();

    for (int off = 1; off < 1024; off <<= 1) {
        int v = (t >= off) ? sums[t - off] : 0;
        __syncthreads();
        sums[t] += v;
        __syncthreads();
    }

    int run = (t == 0) ? 0 : sums[t - 1];
    for (int i = begin; i < end && i < N_NODES; ++i) {
        offsets[i] = run;
        cursor[i]  = run;
        run += counts[i];
    }
}

// Kernel 3: scatter edge srcs into dst-sorted order.
__global__ void __launch_bounds__(256) sort_kernel(
        const int* __restrict__ edge_src,
        const int* __restrict__ edge_dst,
        int* __restrict__ cursor,
        int* __restrict__ sorted_src, int E) {
    int i = blockIdx.x * 256 + threadIdx.x;
    if (i < E) {
        int p = atomicAdd(&cursor[edge_dst[i]], 1);
        sorted_src[p] = edge_src[i];
    }
}

// Kernel 4: fused gather + residual + projection + normalize + ReLU.
// One wave per node; lane l holds pooled[l] then produces out[n][l].
// Edge ids for the bucket are loaded 64-at-a-time (coalesced) and broadcast
// via __shfl; each gather read is a 256 B coalesced row from L2/IF$-resident x.
__global__ void __launch_bounds__(256) gather_project_kernel(
        const float* __restrict__ x,
        const float* __restrict__ W,
        const float* __restrict__ bias,
        const float* __restrict__ deg,
        const int* __restrict__ offsets,
        const int* __restrict__ counts,
        const int* __restrict__ sorted_src,
        float* __restrict__ out) {
    __shared__ float Wlds[DIM * DIM];
    __shared__ float sp[4][DIM];

    int t = threadIdx.x;
    #pragma unroll
    for (int i = 0; i < 4; ++i) {
        int idx = t * 4 + i * 1024;
        *reinterpret_cast<float4*>(&Wlds[idx]) =
            *reinterpret_cast<const float4*>(&W[idx]);
    }

    int wave = t >> 6;
    int lane = t & 63;
    int node = blockIdx.x * 4 + wave;    // grid = N/4 exactly, no tail

    float acc_feat = x[(size_t)node * DIM + lane];   // residual self-connection
    int start = offsets[node];
    int cnt   = counts[node];

    for (int base = 0; base < cnt; base += 64) {
        int m = cnt - base; if (m > 64) m = 64;
        int id = 0;
        if (base + lane < cnt) id = sorted_src[start + base + lane];
        for (int k = 0; k < m; ++k) {
            int src = __shfl(id, k);
            acc_feat += x[(size_t)src * DIM + lane];
        }
    }

    sp[wave][lane] = acc_feat;
    __syncthreads();   // covers W staging + sp rows

    float acc = bias[lane];
    #pragma unroll
    for (int d = 0; d < DIM; ++d) {
        acc = fmaf(sp[wave][d], Wlds[d * DIM + lane], acc);
    }

    float r = acc / deg[node];
    out[(size_t)node * DIM + lane] = fmaxf(r, 0.0f);
}

extern "C" void kernel_launch(void* const* d_in, const int* in_sizes, int n_in,
                              void* d_out, int out_size, void* d_ws, size_t ws_size,
                              hipStream_t stream) {
    const float* x        = (const float*)d_in[0];
    const float* weight   = (const float*)d_in[1];
    const float* bias     = (const float*)d_in[2];
    const float* node_deg = (const float*)d_in[3];
    const int*   edge_src = (const int*)d_in[4];
    const int*   edge_dst = (const int*)d_in[5];
    float* out = (float*)d_out;
    const int E = in_sizes[4];

    // Workspace layout (ws re-poisoned to 0xAA before every call).
    char* ws = (char*)d_ws;
    int* counts     = (int*)(ws + 0);          // 50000 ints
    int* offsets    = (int*)(ws + 204800);     // 50000 ints
    int* cursor     = (int*)(ws + 409600);     // 50000 ints
    int* sorted_src = (int*)(ws + 614400);     // 800000 ints

    hipMemsetAsync(counts, 0, N_NODES * sizeof(int), stream);

    int eb = (E + 255) / 256;
    hist_kernel<<<eb, 256, 0, stream>>>(edge_dst, counts, E);
    scan_kernel<<<1, 1024, 0, stream>>>(counts, offsets, cursor);
    sort_kernel<<<eb, 256, 0, stream>>>(edge_src, edge_dst, cursor, sorted_src, E);
    gather_project_kernel<<<N_NODES / 4, 256, 0, stream>>>(
        x, weight, bias, node_deg, offsets, counts, sorted_src, out);
}

// Round 3
// 225.462 us; speedup vs baseline: 3.4563x; 1.4897x over previous
//
#include <hip/hip_runtime.h>

#define N_NODES 50000
#define DIM 64
#define SCAN_BLOCKS 196   // ceil(50000 / 256)

// ---------------------------------------------------------------------------
// Counting-sort-by-dst pipeline: hist -> 3-level parallel scan -> scatter to
// sorted order -> fused gather/project.  (R0's 51.2M fp32 global atomics
// wrote through L2 at 16 B each = 819 MB HBM writes; this pipeline has only
// 1.6M int atomics.)
// ---------------------------------------------------------------------------

// Kernel 1: histogram of edge_dst.
__global__ void __launch_bounds__(256) hist_kernel(
        const int* __restrict__ edge_dst, int* __restrict__ counts, int E) {
    int i = blockIdx.x * 256 + threadIdx.x;
    if (i < E) atomicAdd(&counts[edge_dst[i]], 1);
}

// Kernel 2a: per-block reduce of counts (256 bins/block).
__global__ void __launch_bounds__(256) block_reduce_kernel(
        const int* __restrict__ counts, int* __restrict__ bsum) {
    __shared__ int s[256];
    int t = threadIdx.x;
    int i = blockIdx.x * 256 + t;
    s[t] = (i < N_NODES) ? counts[i] : 0;
    __syncthreads();
    for (int off = 128; off > 0; off >>= 1) {
        if (t < off) s[t] += s[t + off];
        __syncthreads();
    }
    if (t == 0) bsum[blockIdx.x] = s[0];
}

// Kernel 2b: single-block exclusive scan of the 196 block sums.
__global__ void __launch_bounds__(256) scan_bsums_kernel(
        const int* __restrict__ bsum, int* __restrict__ bbase) {
    __shared__ int s[256];
    int t = threadIdx.x;
    s[t] = (t < SCAN_BLOCKS) ? bsum[t] : 0;
    __syncthreads();
    for (int off = 1; off < 256; off <<= 1) {
        int u = (t >= off) ? s[t - off] : 0;
        __syncthreads();
        s[t] += u;
        __syncthreads();
    }
    bbase[t] = (t == 0) ? 0 : s[t - 1];
}

// Kernel 2c: per-block exclusive scan + global base -> offsets & cursor.
__global__ void __launch_bounds__(256) block_scan_kernel(
        const int* __restrict__ counts, const int* __restrict__ bbase,
        int* __restrict__ offsets, int* __restrict__ cursor) {
    __shared__ int s[256];
    int t = threadIdx.x;
    int i = blockIdx.x * 256 + t;
    int v = (i < N_NODES) ? counts[i] : 0;
    s[t] = v;
    __syncthreads();
    for (int off = 1; off < 256; off <<= 1) {
        int u = (t >= off) ? s[t - off] : 0;
        __syncthreads();
        s[t] += u;
        __syncthreads();
    }
    if (i < N_NODES) {
        int excl = bbase[blockIdx.x] + s[t] - v;   // inclusive -> exclusive
        offsets[i] = excl;
        cursor[i]  = excl;
    }
}

// Kernel 3: scatter edge srcs into dst-sorted order.
__global__ void __launch_bounds__(256) sort_kernel(
        const int* __restrict__ edge_src,
        const int* __restrict__ edge_dst,
        int* __restrict__ cursor,
        int* __restrict__ sorted_src, int E) {
    int i = blockIdx.x * 256 + threadIdx.x;
    if (i < E) {
        int p = atomicAdd(&cursor[edge_dst[i]], 1);
        sorted_src[p] = edge_src[i];
    }
}

// Kernel 4: fused gather + residual + projection + normalize + ReLU.
// One wave per node; lane l holds pooled[l] then produces out[n][l].
__global__ void __launch_bounds__(256) gather_project_kernel(
        const float* __restrict__ x,
        const float* __restrict__ W,
        const float* __restrict__ bias,
        const float* __restrict__ deg,
        const int* __restrict__ offsets,
        const int* __restrict__ counts,
        const int* __restrict__ sorted_src,
        float* __restrict__ out) {
    __shared__ float Wlds[DIM * DIM];
    __shared__ float sp[4][DIM];

    int t = threadIdx.x;
    #pragma unroll
    for (int i = 0; i < 4; ++i) {
        int idx = t * 4 + i * 1024;
        *reinterpret_cast<float4*>(&Wlds[idx]) =
            *reinterpret_cast<const float4*>(&W[idx]);
    }

    int wave = t >> 6;
    int lane = t & 63;
    int node = blockIdx.x * 4 + wave;    // grid = N/4 exactly, no tail

    float acc_feat = x[(size_t)node * DIM + lane];   // residual self-connection
    int start = offsets[node];
    int cnt   = counts[node];

    for (int base = 0; base < cnt; base += 64) {
        int m = cnt - base; if (m > 64) m = 64;
        int id = 0;
        if (base + lane < cnt) id = sorted_src[start + base + lane];
        for (int k = 0; k < m; ++k) {
            int src = __shfl(id, k);
            acc_feat += x[(size_t)src * DIM + lane];
        }
    }

    sp[wave][lane] = acc_feat;
    __syncthreads();   // covers W staging + sp rows

    float acc = bias[lane];
    #pragma unroll
    for (int d = 0; d < DIM; ++d) {
        acc = fmaf(sp[wave][d], Wlds[d * DIM + lane], acc);
    }

    float r = acc / deg[node];
    out[(size_t)node * DIM + lane] = fmaxf(r, 0.0f);
}

extern "C" void kernel_launch(void* const* d_in, const int* in_sizes, int n_in,
                              void* d_out, int out_size, void* d_ws, size_t ws_size,
                              hipStream_t stream) {
    const float* x        = (const float*)d_in[0];
    const float* weight   = (const float*)d_in[1];
    const float* bias     = (const float*)d_in[2];
    const float* node_deg = (const float*)d_in[3];
    const int*   edge_src = (const int*)d_in[4];
    const int*   edge_dst = (const int*)d_in[5];
    float* out = (float*)d_out;
    const int E = in_sizes[4];

    // Workspace layout (ws re-poisoned to 0xAA before every call).
    char* ws = (char*)d_ws;
    int* counts     = (int*)(ws + 0);          // 50000 ints
    int* offsets    = (int*)(ws + 204800);     // 50000 ints
    int* cursor     = (int*)(ws + 409600);     // 50000 ints
    int* sorted_src = (int*)(ws + 614400);     // 800000 ints
    int* bsum       = (int*)(ws + 3814400);    // 256 ints
    int* bbase      = (int*)(ws + 3815424);    // 256 ints

    hipMemsetAsync(counts, 0, N_NODES * sizeof(int), stream);

    int eb = (E + 255) / 256;
    hist_kernel<<<eb, 256, 0, stream>>>(edge_dst, counts, E);
    block_reduce_kernel<<<SCAN_BLOCKS, 256, 0, stream>>>(counts, bsum);
    scan_bsums_kernel<<<1, 256, 0, stream>>>(bsum, bbase);
    block_scan_kernel<<<SCAN_BLOCKS, 256, 0, stream>>>(counts, bbase, offsets, cursor);
    sort_kernel<<<eb, 256, 0, stream>>>(edge_src, edge_dst, cursor, sorted_src, E);
    gather_project_kernel<<<N_NODES / 4, 256, 0, stream>>>(
        x, weight, bias, node_deg, offsets, counts, sorted_src, out);
}

// Round 4
// 200.954 us; speedup vs baseline: 3.8778x; 1.1220x over previous
//
#include <hip/hip_runtime.h>

#define N_NODES 50000
#define DIM 64
#define SCAN_BLOCKS 196   // ceil(50000 / 256)

// ---------------------------------------------------------------------------
// Counting-sort-by-dst pipeline: hist -> 2-level parallel scan -> scatter to
// sorted order -> fused gather/project (4 edges in flight per wave).
// ---------------------------------------------------------------------------

// Kernel 1: histogram of edge_dst.
__global__ void __launch_bounds__(256) hist_kernel(
        const int* __restrict__ edge_dst, int* __restrict__ counts, int E) {
    int i = blockIdx.x * 256 + threadIdx.x;
    if (i < E) atomicAdd(&counts[edge_dst[i]], 1);
}

// Kernel 2a: per-block reduce of counts (256 bins/block).
__global__ void __launch_bounds__(256) block_reduce_kernel(
        const int* __restrict__ counts, int* __restrict__ bsum) {
    __shared__ int s[256];
    int t = threadIdx.x;
    int i = blockIdx.x * 256 + t;
    s[t] = (i < N_NODES) ? counts[i] : 0;
    __syncthreads();
    for (int off = 128; off > 0; off >>= 1) {
        if (t < off) s[t] += s[t + off];
        __syncthreads();
    }
    if (t == 0) bsum[blockIdx.x] = s[0];
}

// Kernel 2b: per-block exclusive scan; each block derives its own global base
// by reducing the PRECEDING blocks' sums in-LDS (folds the former
// scan_bsums kernel -> one fewer dispatch bubble).
__global__ void __launch_bounds__(256) block_scan_kernel(
        const int* __restrict__ counts, const int* __restrict__ bsum,
        int* __restrict__ offsets, int* __restrict__ cursor) {
    __shared__ int sb[256];
    __shared__ int s[256];
    int t = threadIdx.x;

    // Base = sum of preceding blocks' totals.
    sb[t] = (t < (int)blockIdx.x) ? bsum[t] : 0;   // SCAN_BLOCKS <= 256
    __syncthreads();
    for (int off = 128; off > 0; off >>= 1) {
        if (t < off) sb[t] += sb[t + off];
        __syncthreads();
    }
    int base_val = sb[0];

    int i = blockIdx.x * 256 + t;
    int v = (i < N_NODES) ? counts[i] : 0;
    s[t] = v;
    __syncthreads();
    for (int off = 1; off < 256; off <<= 1) {
        int u = (t >= off) ? s[t - off] : 0;
        __syncthreads();
        s[t] += u;
        __syncthreads();
    }
    if (i < N_NODES) {
        int excl = base_val + s[t] - v;   // inclusive -> exclusive
        offsets[i] = excl;
        cursor[i]  = excl;
    }
}

// Kernel 3: scatter edge srcs into dst-sorted order.
__global__ void __launch_bounds__(256) sort_kernel(
        const int* __restrict__ edge_src,
        const int* __restrict__ edge_dst,
        int* __restrict__ cursor,
        int* __restrict__ sorted_src, int E) {
    int i = blockIdx.x * 256 + threadIdx.x;
    if (i < E) {
        int p = atomicAdd(&cursor[edge_dst[i]], 1);
        sorted_src[p] = edge_src[i];
    }
}

// Kernel 4: fused gather + residual + projection + normalize + ReLU.
// One wave per node. Lane = (q = lane>>4 edge slot, c = lane&15 float4 chunk):
// 4 edges in flight per inner iteration, 1 KB of gather reads per load instr
// (vs 256 B with the 1-edge/iter scheme) -> 4x fewer iterations, 4x MLP.
__global__ void __launch_bounds__(256) gather_project_kernel(
        const float* __restrict__ x,
        const float* __restrict__ W,
        const float* __restrict__ bias,
        const float* __restrict__ deg,
        const int* __restrict__ offsets,
        const int* __restrict__ counts,
        const int* __restrict__ sorted_src,
        float* __restrict__ out) {
    __shared__ float Wlds[DIM * DIM];
    __shared__ float sp[4][DIM];

    int t = threadIdx.x;
    #pragma unroll
    for (int i = 0; i < 4; ++i) {
        int idx = t * 4 + i * 1024;
        *reinterpret_cast<float4*>(&Wlds[idx]) =
            *reinterpret_cast<const float4*>(&W[idx]);
    }

    int wave = t >> 6;
    int lane = t & 63;
    int q = lane >> 4;       // edge slot 0..3
    int c = lane & 15;       // float4 chunk within the 64-float row
    int node = blockIdx.x * 4 + wave;    // grid = N/4 exactly, no tail

    int start = offsets[node];
    int cnt   = counts[node];

    float4 acc = make_float4(0.f, 0.f, 0.f, 0.f);

    for (int base = 0; base < cnt; base += 64) {
        int id = 0;
        if (base + lane < cnt) id = sorted_src[start + base + lane];
        int m = cnt - base; if (m > 64) m = 64;
        for (int k = 0; k < m; k += 4) {
            int src = __shfl(id, k + q);
            if (k + q < m) {
                const float4 v = *reinterpret_cast<const float4*>(
                    x + (size_t)src * DIM + c * 4);
                acc.x += v.x; acc.y += v.y; acc.z += v.z; acc.w += v.w;
            }
        }
    }

    // Cross-quarter reduction: combine the 4 edge-slot partial sums.
    #pragma unroll
    for (int off = 16; off < 64; off <<= 1) {
        acc.x += __shfl_xor(acc.x, off);
        acc.y += __shfl_xor(acc.y, off);
        acc.z += __shfl_xor(acc.z, off);
        acc.w += __shfl_xor(acc.w, off);
    }

    if (q == 0) {
        // Residual self-connection, then stage the pooled row.
        const float4 r = *reinterpret_cast<const float4*>(
            x + (size_t)node * DIM + c * 4);
        sp[wave][c * 4 + 0] = acc.x + r.x;
        sp[wave][c * 4 + 1] = acc.y + r.y;
        sp[wave][c * 4 + 2] = acc.z + r.z;
        sp[wave][c * 4 + 3] = acc.w + r.w;
    }
    __syncthreads();   // covers W staging + sp rows

    float accp = bias[lane];
    #pragma unroll
    for (int d = 0; d < DIM; ++d) {
        accp = fmaf(sp[wave][d], Wlds[d * DIM + lane], accp);
    }

    float r = accp / deg[node];
    out[(size_t)node * DIM + lane] = fmaxf(r, 0.0f);
}

extern "C" void kernel_launch(void* const* d_in, const int* in_sizes, int n_in,
                              void* d_out, int out_size, void* d_ws, size_t ws_size,
                              hipStream_t stream) {
    const float* x        = (const float*)d_in[0];
    const float* weight   = (const float*)d_in[1];
    const float* bias     = (const float*)d_in[2];
    const float* node_deg = (const float*)d_in[3];
    const int*   edge_src = (const int*)d_in[4];
    const int*   edge_dst = (const int*)d_in[5];
    float* out = (float*)d_out;
    const int E = in_sizes[4];

    // Workspace layout (ws re-poisoned to 0xAA before every call).
    char* ws = (char*)d_ws;
    int* counts     = (int*)(ws + 0);          // 50000 ints
    int* offsets    = (int*)(ws + 204800);     // 50000 ints
    int* cursor     = (int*)(ws + 409600);     // 50000 ints
    int* sorted_src = (int*)(ws + 614400);     // 800000 ints
    int* bsum       = (int*)(ws + 3814400);    // 256 ints

    hipMemsetAsync(counts, 0, N_NODES * sizeof(int), stream);

    int eb = (E + 255) / 256;
    hist_kernel<<<eb, 256, 0, stream>>>(edge_dst, counts, E);
    block_reduce_kernel<<<SCAN_BLOCKS, 256, 0, stream>>>(counts, bsum);
    block_scan_kernel<<<SCAN_BLOCKS, 256, 0, stream>>>(counts, bsum, offsets, cursor);
    sort_kernel<<<eb, 256, 0, stream>>>(edge_src, edge_dst, cursor, sorted_src, E);
    gather_project_kernel<<<N_NODES / 4, 256, 0, stream>>>(
        x, weight, bias, node_deg, offsets, counts, sorted_src, out);
}

// Round 5
// 139.890 us; speedup vs baseline: 5.5705x; 1.4365x over previous
//
#include <hip/hip_runtime.h>

#define N_NODES 50000
#define DIM 64
#define CB 196          // coarse buckets = ceil(N/256); bucket = dst >> 8
#define CAP 5120        // per-bucket capacity (mean 4096, sigma ~64 -> +16 sigma)
#define EPT 16          // edges per thread in partition kernel

// ---------------------------------------------------------------------------
// Two-phase locality-preserving counting sort by dst, then fused
// gather/project.  Replaces the single-pass atomic scatter (R3: 52 MB HBM
// writes = one dirty 64B line per 4B store) with:
//   phase A: partition into 196 coarse buckets, per-block contiguous runs
//   phase B: per-bucket LDS sort -> contiguous CSR writes (+ offsets/counts)
// ---------------------------------------------------------------------------

// Phase A: partition edges into coarse buckets. Edge packed as (src<<8)|loc.
__global__ void __launch_bounds__(256) partition_kernel(
        const int* __restrict__ edge_src,
        const int* __restrict__ edge_dst,
        int* __restrict__ bucket_cursor,      // [CB], zeroed
        unsigned int* __restrict__ coarse,    // [CB*CAP]
        int E) {
    __shared__ int lhist[CB];
    __shared__ int lbase[CB];
    int t = threadIdx.x;
    for (int i = t; i < CB; i += 256) lhist[i] = 0;
    __syncthreads();

    int base_e = blockIdx.x * (256 * EPT);
    unsigned int pk[EPT];
    int bk[EPT];
    #pragma unroll
    for (int j = 0; j < EPT; ++j) {
        int e = base_e + j * 256 + t;         // coalesced
        bk[j] = -1;
        if (e < E) {
            int s = edge_src[e];
            int d = edge_dst[e];
            bk[j] = d >> 8;
            pk[j] = ((unsigned int)s << 8) | (unsigned int)(d & 255);
            atomicAdd(&lhist[bk[j]], 1);
        }
    }
    __syncthreads();

    // Reserve contiguous per-bucket ranges; reuse lhist as local rank cursor.
    for (int i = t; i < CB; i += 256) {
        lbase[i] = atomicAdd(&bucket_cursor[i], lhist[i]);
        lhist[i] = 0;
    }
    __syncthreads();

    #pragma unroll
    for (int j = 0; j < EPT; ++j) {
        if (bk[j] >= 0) {
            int r = atomicAdd(&lhist[bk[j]], 1);
            coarse[(size_t)bk[j] * CAP + lbase[bk[j]] + r] = pk[j];
        }
    }
}

// Phase B: one block per coarse bucket. Finishes the sort in LDS and emits
// offsets[] / counts[] / sorted_src[] for its 256 nodes. All sorted_src
// writes land in this block's contiguous output range -> write-combined.
__global__ void __launch_bounds__(512) bucket_sort_kernel(
        const int* __restrict__ bucket_cursor,
        const unsigned int* __restrict__ coarse,
        int* __restrict__ offsets,
        int* __restrict__ counts,
        int* __restrict__ sorted_src) {
    __shared__ int red[256];
    __shared__ int hist[256];
    __shared__ int excl[256];
    __shared__ int cur[256];
    int t = threadIdx.x;
    int b = blockIdx.x;

    // Global base = sum of preceding buckets' totals (CB <= 256).
    if (t < 256) red[t] = (t < b) ? bucket_cursor[t] : 0;
    __syncthreads();
    for (int off = 128; off > 0; off >>= 1) {
        if (t < off) red[t] += red[t + off];
        __syncthreads();
    }
    int gbase = red[0];
    int cnt_b = bucket_cursor[b];

    if (t < 256) hist[t] = 0;
    __syncthreads();
    for (int i = t; i < cnt_b; i += 512) {
        unsigned int e = coarse[(size_t)b * CAP + i];
        atomicAdd(&hist[e & 255u], 1);
    }
    __syncthreads();

    // Inclusive Hillis-Steele over 256 bins, then convert to exclusive.
    if (t < 256) excl[t] = hist[t];
    __syncthreads();
    for (int off = 1; off < 256; off <<= 1) {
        int u = 0;
        if (t < 256 && t >= off) u = excl[t - off];
        __syncthreads();
        if (t < 256) excl[t] += u;
        __syncthreads();
    }
    if (t < 256) {
        int ex = excl[t] - hist[t];
        cur[t] = ex;
        int node = b * 256 + t;
        if (node < N_NODES) {
            offsets[node] = gbase + ex;
            counts[node]  = hist[t];
        }
    }
    __syncthreads();

    for (int i = t; i < cnt_b; i += 512) {
        unsigned int e = coarse[(size_t)b * CAP + i];
        int bin = (int)(e & 255u);
        int p = atomicAdd(&cur[bin], 1);
        sorted_src[gbase + p] = (int)(e >> 8);
    }
}

// Fused gather + residual + projection + normalize + ReLU (unchanged R3).
// One wave per node. Lane = (q = lane>>4 edge slot, c = lane&15 float4 chunk).
__global__ void __launch_bounds__(256) gather_project_kernel(
        const float* __restrict__ x,
        const float* __restrict__ W,
        const float* __restrict__ bias,
        const float* __restrict__ deg,
        const int* __restrict__ offsets,
        const int* __restrict__ counts,
        const int* __restrict__ sorted_src,
        float* __restrict__ out) {
    __shared__ float Wlds[DIM * DIM];
    __shared__ float sp[4][DIM];

    int t = threadIdx.x;
    #pragma unroll
    for (int i = 0; i < 4; ++i) {
        int idx = t * 4 + i * 1024;
        *reinterpret_cast<float4*>(&Wlds[idx]) =
            *reinterpret_cast<const float4*>(&W[idx]);
    }

    int wave = t >> 6;
    int lane = t & 63;
    int q = lane >> 4;
    int c = lane & 15;
    int node = blockIdx.x * 4 + wave;    // grid = N/4 exactly

    int start = offsets[node];
    int cnt   = counts[node];

    float4 acc = make_float4(0.f, 0.f, 0.f, 0.f);

    for (int base = 0; base < cnt; base += 64) {
        int id = 0;
        if (base + lane < cnt) id = sorted_src[start + base + lane];
        int m = cnt - base; if (m > 64) m = 64;
        for (int k = 0; k < m; k += 4) {
            int src = __shfl(id, k + q);
            if (k + q < m) {
                const float4 v = *reinterpret_cast<const float4*>(
                    x + (size_t)src * DIM + c * 4);
                acc.x += v.x; acc.y += v.y; acc.z += v.z; acc.w += v.w;
            }
        }
    }

    #pragma unroll
    for (int off = 16; off < 64; off <<= 1) {
        acc.x += __shfl_xor(acc.x, off);
        acc.y += __shfl_xor(acc.y, off);
        acc.z += __shfl_xor(acc.z, off);
        acc.w += __shfl_xor(acc.w, off);
    }

    if (q == 0) {
        const float4 r = *reinterpret_cast<const float4*>(
            x + (size_t)node * DIM + c * 4);
        sp[wave][c * 4 + 0] = acc.x + r.x;
        sp[wave][c * 4 + 1] = acc.y + r.y;
        sp[wave][c * 4 + 2] = acc.z + r.z;
        sp[wave][c * 4 + 3] = acc.w + r.w;
    }
    __syncthreads();

    float accp = bias[lane];
    #pragma unroll
    for (int d = 0; d < DIM; ++d) {
        accp = fmaf(sp[wave][d], Wlds[d * DIM + lane], accp);
    }

    float r = accp / deg[node];
    out[(size_t)node * DIM + lane] = fmaxf(r, 0.0f);
}

extern "C" void kernel_launch(void* const* d_in, const int* in_sizes, int n_in,
                              void* d_out, int out_size, void* d_ws, size_t ws_size,
                              hipStream_t stream) {
    const float* x        = (const float*)d_in[0];
    const float* weight   = (const float*)d_in[1];
    const float* bias     = (const float*)d_in[2];
    const float* node_deg = (const float*)d_in[3];
    const int*   edge_src = (const int*)d_in[4];
    const int*   edge_dst = (const int*)d_in[5];
    float* out = (float*)d_out;
    const int E = in_sizes[4];

    // Workspace layout (re-poisoned to 0xAA before every call).
    char* ws = (char*)d_ws;
    int*          bucket_cursor = (int*)(ws + 0);            // CB ints
    unsigned int* coarse        = (unsigned int*)(ws + 1024);          // CB*CAP
    int*          offsets       = (int*)(ws + 1024 + 4014080);         // N ints
    int*          counts        = (int*)(ws + 1024 + 4014080 + 200000);
    int*          sorted_src    = (int*)(ws + 1024 + 4014080 + 400000);

    hipMemsetAsync(bucket_cursor, 0, CB * sizeof(int), stream);

    int pa_blocks = (E + 256 * EPT - 1) / (256 * EPT);   // 196
    partition_kernel<<<pa_blocks, 256, 0, stream>>>(
        edge_src, edge_dst, bucket_cursor, coarse, E);
    bucket_sort_kernel<<<CB, 512, 0, stream>>>(
        bucket_cursor, coarse, offsets, counts, sorted_src);
    gather_project_kernel<<<N_NODES / 4, 256, 0, stream>>>(
        x, weight, bias, node_deg, offsets, counts, sorted_src, out);
}